// Round 6
// baseline (402.769 us; speedup 1.0000x reference)
//
#include <hip/hip_runtime.h>
#include <hip/hip_bf16.h>

#define Bd 4
#define Nd 2048
#define Cd 1024
#define Hd 16
#define Dd 64
#define Rd 16
#define KAUG 1056     // 1024 + 16 lora + 16 zero pad
#define SCALEf 0.125f
#define PIT 72        // attn LDS pitch (bf16)

using short8 = __attribute__((ext_vector_type(8))) short;
using f32x4  = __attribute__((ext_vector_type(4))) float;

// bit-exact RNE fp32->bf16 (ties-to-even), ~3 VALU instead of libdevice's ~5
static __device__ __forceinline__ ushort bf_rn(float f) {
    const uint u = __float_as_uint(f);
    return (ushort)((u + 0x7FFFu + ((u >> 16) & 1u)) >> 16);
}

// async global->LDS, 16B per lane; LDS dest = wave-uniform base + lane*16
#define GLOAD_LDS16(g, l) __builtin_amdgcn_global_load_lds( \
    (const __attribute__((address_space(1))) void*)(g),      \
    (__attribute__((address_space(3))) void*)(l), 16, 0, 0)

// ---------------- pack A: Aaug[row][0..1023] = bf16(query row) -----------------
__global__ __launch_bounds__(256) void pack_a_kernel(
    const float* __restrict__ query, ushort* __restrict__ Aaug)
{
    const int row = blockIdx.x;
    const int t = threadIdx.x;
    const float4 v = *(const float4*)&query[(size_t)row * Cd + t * 4];
    ushort4 u;
    u.x = bf_rn(v.x); u.y = bf_rn(v.y); u.z = bf_rn(v.z); u.w = bf_rn(v.w);
    *(ushort4*)&Aaug[(size_t)row * KAUG + t * 4] = u;
}

// ---------------- pack W_loraA^T: WAT[r][c] = bf16(WloraA[c][r]) ---------------
__global__ __launch_bounds__(256) void pack_wat_kernel(
    const float* __restrict__ WA, ushort* __restrict__ WAT)
{
    const int idx = blockIdx.x * 256 + threadIdx.x;   // 16384
    const int c = idx >> 4, r = idx & 15;
    WAT[r * 1024 + c] = bf_rn(WA[idx]);
}

// ---------------- lora MFMA: Aaug[row][1024+r] = bf16(query_row . WloraA[:,r]) -
__global__ __launch_bounds__(64) void lora_mfma_kernel(
    const ushort* __restrict__ Aro, const ushort* __restrict__ WAT,
    ushort* __restrict__ Awr)
{
    const int lane = threadIdx.x;
    const int quad = lane >> 4, lc = lane & 15;
    const int row0 = blockIdx.x * 16;
    f32x4 acc = {0.f, 0.f, 0.f, 0.f};
    #pragma unroll 4
    for (int k0 = 0; k0 < 1024; k0 += 32) {
        const short8 a = *(const short8*)&Aro[(size_t)(row0 + lc) * KAUG + k0 + quad * 8];
        const short8 b = *(const short8*)&WAT[lc * 1024 + k0 + quad * 8];
        acc = __builtin_amdgcn_mfma_f32_16x16x32_bf16(a, b, acc, 0, 0, 0);
    }
    #pragma unroll
    for (int ri = 0; ri < 4; ++ri) {
        const size_t row = row0 + quad * 4 + ri;
        Awr[row * KAUG + 1024 + lc] = bf_rn(acc[ri]);
        Awr[row * KAUG + 1040 + lc] = 0;
    }
}

// ---------------- pack B for qkv: BaugT[n][k], k-major bf16 -------------------
__global__ __launch_bounds__(256) void pack_bqkv_kernel(
    const float* __restrict__ Wqkv, const float* __restrict__ WloraB,
    const float* __restrict__ magnitude, ushort* __restrict__ BT)
{
    __shared__ float tile[32][33];
    const int k0 = blockIdx.x * 32, n0 = blockIdx.y * 32;
    const int tx = threadIdx.x & 31, ty = threadIdx.x >> 5;   // 32 x 8
    #pragma unroll
    for (int i = 0; i < 4; ++i) {
        const int k = k0 + ty + i * 8;
        const int n = n0 + tx;
        float v;
        if (k < 1024)                      v = Wqkv[(size_t)k * 3072 + n];
        else if (k < 1040 && n < 1024)     v = magnitude[n >> 6] * WloraB[(k - 1024) * Cd + n];
        else                               v = 0.f;
        tile[ty + i * 8][tx] = v;
    }
    __syncthreads();
    #pragma unroll
    for (int i = 0; i < 4; ++i) {
        const int n = n0 + ty + i * 8;
        const int k = k0 + tx;
        BT[(size_t)n * KAUG + k] = bf_rn(tile[tx][ty + i * 8]);
    }
}

// ---------------- pack B for proj: WpT[n][k] = bf16(Wproj[k][n]) ---------------
__global__ __launch_bounds__(256) void pack_bproj_kernel(
    const float* __restrict__ Wp, ushort* __restrict__ BT)
{
    __shared__ float tile[32][33];
    const int k0 = blockIdx.x * 32, n0 = blockIdx.y * 32;
    const int tx = threadIdx.x & 31, ty = threadIdx.x >> 5;
    #pragma unroll
    for (int i = 0; i < 4; ++i)
        tile[ty + i * 8][tx] = Wp[(size_t)(k0 + ty + i * 8) * Cd + n0 + tx];
    __syncthreads();
    #pragma unroll
    for (int i = 0; i < 4; ++i)
        BT[(size_t)(n0 + ty + i * 8) * Cd + k0 + tx] = bf_rn(tile[tx][ty + i * 8]);
}

// ---------------- MFMA bf16 GEMM, 128x128 tile, BK=32 (m97 structure) ---------
template <int KD, int MODE>
__global__ __launch_bounds__(256) void mfma_gemm_kernel(
    const ushort* __restrict__ Ag, const ushort* __restrict__ Bg,
    ushort* __restrict__ qb, ushort* __restrict__ kb, ushort* __restrict__ vb,
    float* __restrict__ outf)
{
    __shared__ ushort As[128 * 32];
    __shared__ ushort Bs[128 * 32];
    const int t = threadIdx.x;
    const int w = t >> 6, lane = t & 63, quad = lane >> 4, lc = lane & 15;
    const int wm = w >> 1, wn = w & 1;
    const int m0 = blockIdx.y * 128, n0 = blockIdx.x * 128;

    f32x4 acc[4][4] = {};

    const int lin0 = t, lin1 = t + 256;
    const int rowT0 = lin0 >> 2, kc0 = (lin0 & 3) * 8;
    const int rowT1 = lin1 >> 2, kc1 = (lin1 & 3) * 8;

    for (int k0 = 0; k0 < KD; k0 += 32) {
        GLOAD_LDS16(&Ag[(size_t)(m0 + rowT0) * KD + k0 + kc0], &As[lin0 * 8]);
        GLOAD_LDS16(&Ag[(size_t)(m0 + rowT1) * KD + k0 + kc1], &As[lin1 * 8]);
        GLOAD_LDS16(&Bg[(size_t)(n0 + rowT0) * KD + k0 + kc0], &Bs[lin0 * 8]);
        GLOAD_LDS16(&Bg[(size_t)(n0 + rowT1) * KD + k0 + kc1], &Bs[lin1 * 8]);
        __syncthreads();
        short8 a[4], b[4];
        #pragma unroll
        for (int i = 0; i < 4; ++i)
            a[i] = *(const short8*)&As[(wm * 64 + i * 16 + lc) * 32 + quad * 8];
        #pragma unroll
        for (int j = 0; j < 4; ++j)
            b[j] = *(const short8*)&Bs[(wn * 64 + j * 16 + lc) * 32 + quad * 8];
        #pragma unroll
        for (int i = 0; i < 4; ++i)
            #pragma unroll
            for (int j = 0; j < 4; ++j)
                acc[i][j] = __builtin_amdgcn_mfma_f32_16x16x32_bf16(a[i], b[j], acc[i][j], 0, 0, 0);
        __syncthreads();
    }

    if (MODE == 0) {
        const int sec = n0 >> 10;
        ushort* dst = sec == 0 ? qb : (sec == 1 ? kb : vb);
        #pragma unroll
        for (int i = 0; i < 4; ++i)
            #pragma unroll
            for (int j = 0; j < 4; ++j) {
                const int gcol = (n0 & 1023) + wn * 64 + j * 16 + lc;
                const int h = gcol >> 6, d = gcol & 63;
                #pragma unroll
                for (int r = 0; r < 4; ++r) {
                    const int grow = m0 + wm * 64 + i * 16 + quad * 4 + r;
                    const int b_ = grow >> 11, n_ = grow & 2047;
                    dst[(((size_t)(b_ * Hd) + h) * Nd + n_) * Dd + d] = bf_rn(acc[i][j][r]);
                }
            }
    } else {
        #pragma unroll
        for (int i = 0; i < 4; ++i)
            #pragma unroll
            for (int j = 0; j < 4; ++j) {
                const int gcol = n0 + wn * 64 + j * 16 + lc;
                #pragma unroll
                for (int r = 0; r < 4; ++r) {
                    const int grow = m0 + wm * 64 + i * 16 + quad * 4 + r;
                    outf[(size_t)grow * Cd + gcol] = acc[i][j][r];
                }
            }
    }
}

// ---------------- MFMA bf16 flash attention, fixed-base softmax ---------------
// l computed on the matrix pipe via a ones-vector B fragment (rowsum MFMA).
__global__ __launch_bounds__(256) void attn_mfma_kernel(
    const ushort* __restrict__ qbuf, const ushort* __restrict__ kbuf,
    const ushort* __restrict__ vbuf, const float* __restrict__ mask,
    ushort* __restrict__ attn_out)
{
    __shared__ short Qs[64 * PIT];
    __shared__ short Ks[64 * PIT];
    __shared__ short Vts[64 * PIT];
    __shared__ short Ps[64 * PIT];

    const int t = threadIdx.x;
    const int w = t >> 6, lane = t & 63;
    const int quad = lane >> 4, lc = lane & 15;
    const int bh = blockIdx.y, b = bh >> 4, h = bh & 15;
    const int n0 = blockIdx.x * 64;

    const short* qg = (const short*)qbuf + (size_t)bh * Nd * Dd;
    const short* kg = (const short*)kbuf + (size_t)bh * Nd * Dd;
    const short* vg = (const short*)vbuf + (size_t)bh * Nd * Dd;

    {
        const int row = t >> 2, dblk = (t & 3) * 16;
        *(int4*)&Qs[row * PIT + dblk]     = *(const int4*)&qg[(n0 + row) * Dd + dblk];
        *(int4*)&Qs[row * PIT + dblk + 8] = *(const int4*)&qg[(n0 + row) * Dd + dblk + 8];
    }

    const int rowg = w * 16 + quad * 4;

    // per-r mask row pointers: per-tile addressing becomes uniform (SGPR) adds
    const float* mp[4];
    #pragma unroll
    for (int r = 0; r < 4; ++r)
        mp[r] = mask + ((size_t)b * Nd + n0 + rowg + r) * Nd + lc;

    f32x4 o[4];
    #pragma unroll
    for (int dt = 0; dt < 4; ++dt) o[dt] = (f32x4){0.f, 0.f, 0.f, 0.f};
    f32x4 acc_l = {0.f, 0.f, 0.f, 0.f};

    short8 bones;
    #pragma unroll
    for (int i = 0; i < 8; ++i) bones[i] = (short)0x3F80;   // bf16 1.0

    for (int m0 = 0; m0 < Nd; m0 += 64) {
        {
            const int row = t >> 2, dblk = (t & 3) * 16;
            *(int4*)&Ks[row * PIT + dblk]     = *(const int4*)&kg[(m0 + row) * Dd + dblk];
            *(int4*)&Ks[row * PIT + dblk + 8] = *(const int4*)&kg[(m0 + row) * Dd + dblk + 8];
        }
        {
            const int kv0 = (t >> 3) * 2;
            const int dg = t & 7, d0 = dg * 8;
            ushort u0[8], u1[8];
            *(int4*)u0 = *(const int4*)&vg[(m0 + kv0) * Dd + d0];
            *(int4*)u1 = *(const int4*)&vg[(m0 + kv0 + 1) * Dd + d0];
            const int blk = ((kv0 >> 3) ^ dg) & 7;
            #pragma unroll
            for (int i = 0; i < 8; ++i) {
                *(uint*)&Vts[(d0 + i) * PIT + blk * 8 + (kv0 & 7)] =
                    (uint)u0[i] | ((uint)u1[i] << 16);
            }
        }
        float mk[4][4];
        #pragma unroll
        for (int r = 0; r < 4; ++r)
            #pragma unroll
            for (int nt = 0; nt < 4; ++nt)
                mk[r][nt] = mp[r][m0 + nt * 16];
        __syncthreads();

        // ---- S = Q K^T ----
        f32x4 s[4];
        #pragma unroll
        for (int nt = 0; nt < 4; ++nt) s[nt] = (f32x4){0.f, 0.f, 0.f, 0.f};
        #pragma unroll
        for (int ks = 0; ks < 2; ++ks) {
            const short8 a = *(const short8*)&Qs[(w * 16 + lc) * PIT + ks * 32 + quad * 8];
            #pragma unroll
            for (int nt = 0; nt < 4; ++nt) {
                const short8 bb = *(const short8*)&Ks[(nt * 16 + lc) * PIT + ks * 32 + quad * 8];
                s[nt] = __builtin_amdgcn_mfma_f32_16x16x32_bf16(a, bb, s[nt], 0, 0, 0);
            }
        }
        // ---- P = exp(S*scale + mask); store swizzled P^bf16 ----
        #pragma unroll
        for (int nt = 0; nt < 4; ++nt) {
            const int cbx = ((nt * 2 + (lc >> 3)) ^ quad) * 8 + (lc & 7);
            #pragma unroll
            for (int r = 0; r < 4; ++r) {
                const float p = __expf(fmaf(s[nt][r], SCALEf, mk[r][nt]));
                Ps[(rowg + r) * PIT + cbx] = (short)bf_rn(p);
            }
        }
        // ---- O += P V ; l += P @ ones (matrix pipe) ----
        #pragma unroll
        for (int ks = 0; ks < 2; ++ks) {
            const int pblk = (((ks * 4 + quad) ^ ((lc >> 2) & 3)) & 7) * 8;
            const short8 a = *(const short8*)&Ps[(w * 16 + lc) * PIT + pblk];
            acc_l = __builtin_amdgcn_mfma_f32_16x16x32_bf16(a, bones, acc_l, 0, 0, 0);
            #pragma unroll
            for (int dt = 0; dt < 4; ++dt) {
                const int d = dt * 16 + lc;
                const int blk = (ks * 4 + quad) ^ ((d >> 3) & 7);
                const short8 bb = *(const short8*)&Vts[d * PIT + blk * 8];
                o[dt] = __builtin_amdgcn_mfma_f32_16x16x32_bf16(a, bb, o[dt], 0, 0, 0);
            }
        }
        __syncthreads();
    }

    // epilogue: l is ready per-lane in acc_l (all lc columns identical)
    #pragma unroll
    for (int r = 0; r < 4; ++r) {
        const float inv = 1.f / acc_l[r];
        const size_t rowo = ((size_t)(b * Nd + n0 + rowg + r)) * Cd + h * Dd;
        #pragma unroll
        for (int dt = 0; dt < 4; ++dt)
            attn_out[rowo + dt * 16 + lc] = bf_rn(o[dt][r] * inv);
    }
}

extern "C" void kernel_launch(void* const* d_in, const int* in_sizes, int n_in,
                              void* d_out, int out_size, void* d_ws, size_t ws_size,
                              hipStream_t stream) {
    const float* query     = (const float*)d_in[0];
    const float* mask      = (const float*)d_in[1];
    const float* Wqkv      = (const float*)d_in[2];
    const float* magnitude = (const float*)d_in[3];
    const float* WloraA    = (const float*)d_in[4];
    const float* WloraB    = (const float*)d_in[5];
    const float* Wproj     = (const float*)d_in[6];
    float* out = (float*)d_out;

    const size_t SZ = (size_t)Bd * Hd * Nd * Dd;       // 8M elements
    char* p = (char*)d_ws;
    ushort* qbuf = (ushort*)p;           p += SZ * 2;
    ushort* kbuf = (ushort*)p;           p += SZ * 2;
    ushort* vbuf = (ushort*)p;           p += SZ * 2;
    ushort* aout = (ushort*)p;           p += SZ * 2;
    ushort* Aaug = (ushort*)p;           p += (size_t)8192 * KAUG * 2;
    ushort* BT   = (ushort*)p;           p += (size_t)3072 * KAUG * 2;
    ushort* WpT  = (ushort*)p;           p += (size_t)1024 * 1024 * 2;
    ushort* WAT  = (ushort*)p;           p += (size_t)16 * 1024 * 2;

    pack_a_kernel<<<dim3(Bd * Nd), 256, 0, stream>>>(query, Aaug);
    pack_wat_kernel<<<dim3(64), 256, 0, stream>>>(WloraA, WAT);
    pack_bqkv_kernel<<<dim3(KAUG / 32, 3072 / 32), 256, 0, stream>>>(
        Wqkv, WloraB, magnitude, BT);
    pack_bproj_kernel<<<dim3(32, 32), 256, 0, stream>>>(Wproj, WpT);
    lora_mfma_kernel<<<dim3(512), 64, 0, stream>>>(Aaug, WAT, Aaug);
    mfma_gemm_kernel<KAUG, 0><<<dim3(24, 64), 256, 0, stream>>>(
        Aaug, BT, qbuf, kbuf, vbuf, nullptr);
    attn_mfma_kernel<<<dim3(Nd / 64, Bd * Hd), 256, 0, stream>>>(
        qbuf, kbuf, vbuf, mask, aout);
    mfma_gemm_kernel<1024, 1><<<dim3(8, 64), 256, 0, stream>>>(
        aout, WpT, nullptr, nullptr, nullptr, out);
}